// Round 4
// baseline (109.476 us; speedup 1.0000x reference)
//
#include <hip/hip_runtime.h>
#include <stdint.h>

#define NFEAT  16
#define NCOLS  969   // 1 bias + 16 deg1 + 136 deg2 + 816 deg3
#define NROWS  65536

typedef float floatx4 __attribute__((ext_vector_type(4)));

// ---------------------------------------------------------------------------
// One wave handles a 64-row x 64-col output tile (last chunk: 64 x 9).
// Lane l owns row l of the tile: all 16 x-values in registers, every column's
// (i,j,k) combo is a compile-time constant (static unroll) -> ~1 mul/element,
// no table, no gathers, no branches.
// Transpose through a per-wave XOR-swizzled LDS tile so global stores are
// fully contiguous 256B/wave dword stores (row stride 3876B is only 4B-
// aligned, so row-wise dwordx4 is not possible).
//   LDS phys dword index: row*64 + (col ^ ((row&15)<<2))
// Same-wave LDS write->read needs no barrier (in-order LDS pipe).
// ---------------------------------------------------------------------------

template<int CBASE, int NC>
__device__ __forceinline__ void do_chunk(const float xr[NFEAT],
                                         float* tl, int lane,
                                         float* __restrict__ outp) {
    float v[NC];
    int col = 0;
    // EMIT runs over all 969 columns in reference order; out-of-chunk emits
    // are dead-code-eliminated after unrolling (col is a post-unroll constant).
#define EMIT(P) do { if (col >= CBASE && col < CBASE + NC) { v[col - CBASE] = (P); } ++col; } while (0)
    EMIT(1.0f);                                   // bias
    #pragma unroll
    for (int i = 0; i < NFEAT; ++i) EMIT(xr[i]);  // degree 1
    #pragma unroll
    for (int i = 0; i < NFEAT; ++i)               // degree 2
        #pragma unroll
        for (int j = i; j < NFEAT; ++j) EMIT(xr[i] * xr[j]);
    #pragma unroll
    for (int i = 0; i < NFEAT; ++i)               // degree 3
        #pragma unroll
        for (int j = i; j < NFEAT; ++j)
            #pragma unroll
            for (int k = j; k < NFEAT; ++k) EMIT(xr[i] * xr[j] * xr[k]);
#undef EMIT

    // ---- write swizzled LDS tile (lane = tile row) ----
    const int sw = (lane & 15) << 2;
    const int rowoff = lane << 6;
    #pragma unroll
    for (int c4 = 0; c4 < NC / 4; ++c4) {
        floatx4 p;
        p[0] = v[c4 * 4 + 0];
        p[1] = v[c4 * 4 + 1];
        p[2] = v[c4 * 4 + 2];
        p[3] = v[c4 * 4 + 3];
        *(floatx4*)&tl[rowoff + ((c4 * 4) ^ sw)] = p;   // ds_write_b128, swizzled
    }
    #pragma unroll
    for (int c = (NC / 4) * 4; c < NC; ++c)
        tl[rowoff + (c ^ sw)] = v[c];                   // ragged tail (chunk 15)

    // ---- coalesced store phase: one 64-col row per wave-iteration ----
    #pragma unroll 8
    for (int r = 0; r < 64; ++r) {
        float val = tl[(r << 6) + (lane ^ ((r & 15) << 2))];
        if (NC == 64 || lane < NC)
            __builtin_nontemporal_store(val, outp + (size_t)r * NCOLS + CBASE + lane);
    }
}

__global__ void __launch_bounds__(256)
poly_tile(const float* __restrict__ x, float* __restrict__ out) {
    __shared__ float tile[4][64 * 64];   // 16 KiB per wave, 64 KiB per block

    const int wid  = threadIdx.x >> 6;
    const int lane = threadIdx.x & 63;
    const int gw     = blockIdx.x * 4 + wid;   // global wave id, 0..16383
    const int chunk  = gw & 15;                // column chunk 0..15
    const int rowgrp = gw >> 4;                // row group 0..1023

    const int row = (rowgrp << 6) + lane;
    const floatx4* xv = (const floatx4*)(x + ((size_t)row << 4));
    floatx4 x0 = xv[0], x1 = xv[1], x2 = xv[2], x3 = xv[3];
    float xr[NFEAT] = {x0[0], x0[1], x0[2], x0[3],
                       x1[0], x1[1], x1[2], x1[3],
                       x2[0], x2[1], x2[2], x2[3],
                       x3[0], x3[1], x3[2], x3[3]};

    float* outp = out + (size_t)(rowgrp << 6) * NCOLS;
    float* tl = tile[wid];

    switch (chunk) {
        case  0: do_chunk<  0, 64>(xr, tl, lane, outp); break;
        case  1: do_chunk< 64, 64>(xr, tl, lane, outp); break;
        case  2: do_chunk<128, 64>(xr, tl, lane, outp); break;
        case  3: do_chunk<192, 64>(xr, tl, lane, outp); break;
        case  4: do_chunk<256, 64>(xr, tl, lane, outp); break;
        case  5: do_chunk<320, 64>(xr, tl, lane, outp); break;
        case  6: do_chunk<384, 64>(xr, tl, lane, outp); break;
        case  7: do_chunk<448, 64>(xr, tl, lane, outp); break;
        case  8: do_chunk<512, 64>(xr, tl, lane, outp); break;
        case  9: do_chunk<576, 64>(xr, tl, lane, outp); break;
        case 10: do_chunk<640, 64>(xr, tl, lane, outp); break;
        case 11: do_chunk<704, 64>(xr, tl, lane, outp); break;
        case 12: do_chunk<768, 64>(xr, tl, lane, outp); break;
        case 13: do_chunk<832, 64>(xr, tl, lane, outp); break;
        case 14: do_chunk<896, 64>(xr, tl, lane, outp); break;
        case 15: do_chunk<960,  9>(xr, tl, lane, outp); break;
    }
}

extern "C" void kernel_launch(void* const* d_in, const int* in_sizes, int n_in,
                              void* d_out, int out_size, void* d_ws, size_t ws_size,
                              hipStream_t stream) {
    const float* x = (const float*)d_in[0];
    float* out = (float*)d_out;

    // 65536 rows / 64 rows-per-wave = 1024 row groups; x 16 chunks = 16384
    // waves; 4 waves per block -> 4096 blocks.
    poly_tile<<<4096, 256, 0, stream>>>(x, out);
}

// Round 5
// 84.581 us; speedup vs baseline: 1.2943x; 1.2943x over previous
//
#include <hip/hip_runtime.h>
#include <stdint.h>

#define NFEAT 16
#define NCOLS 969        // 1 bias + 16 deg1 + 136 deg2 + 816 deg3
#define NROWS 65536
#define SROWS (NROWS / 4)        // 16384 superrows of 4 rows
#define GPS   NCOLS              // float4 groups per superrow (4*969/4)
#define XPAD  17                 // padded x row stride; xp[r][16] = 1.0f

typedef float floatx4 __attribute__((ext_vector_type(4)));

// --------------------------------------------------------------------------
// col -> (i,j,k) feature indices, 16 = "the 1.0f pad slot" (bias / unused).
// Ordering matches sklearn/jax PolynomialFeatures (verified absmax 0.0 in R1/R3).
// --------------------------------------------------------------------------
__device__ __forceinline__ void decode_col(int col, int* pi, int* pj, int* pk) {
    int i = 16, j = 16, k = 16;
    if (col == 0) {
        // bias
    } else if (col <= NFEAT) {
        i = col - 1;
    } else if (col <= NFEAT + (NFEAT * (NFEAT + 1)) / 2) {
        int c = col - (NFEAT + 1), a = 0;
        while (c >= NFEAT - a) { c -= NFEAT - a; ++a; }
        i = a; j = a + c;
    } else {
        int c = col - (NFEAT + 1 + (NFEAT * (NFEAT + 1)) / 2), a = 0;
        while (c >= ((NFEAT - a) * (NFEAT + 1 - a)) / 2) {
            c -= ((NFEAT - a) * (NFEAT + 1 - a)) / 2; ++a;
        }
        int b = a;
        while (c >= NFEAT - b) { c -= NFEAT - b; ++b; }
        i = a; j = b; k = b + c;
    }
    *pi = i; *pj = j; *pk = k;
}

// Packed per-element gather offsets for one superrow (4*969 entries).
// offset = row_in_super*68 + idx*4 (bytes into xp superrow), 9 bits each.
__global__ void build_packed(uint32_t* __restrict__ ptbl) {
    int t = blockIdx.x * blockDim.x + threadIdx.x;
    if (t >= 4 * NCOLS) return;
    int rins = t / NCOLS;
    int col  = t - rins * NCOLS;
    int i, j, k;
    decode_col(col, &i, &j, &k);
    uint32_t base = (uint32_t)rins * (XPAD * 4);
    uint32_t oi = base + (uint32_t)i * 4;
    uint32_t oj = base + (uint32_t)j * 4;
    uint32_t ok = base + (uint32_t)k * 4;
    ptbl[t] = oi | (oj << 9) | (ok << 18);
}

// Padded copy of x: xp[row][0..15] = x row, xp[row][16] = 1.0f.
__global__ void build_xp(const float* __restrict__ x, float* __restrict__ xp) {
    int t = blockIdx.x * blockDim.x + threadIdx.x;
    if (t >= NROWS * XPAD) return;
    int row = t / XPAD;
    int c = t - row * XPAD;
    xp[t] = (c < NFEAT) ? x[row * NFEAT + c] : 1.0f;
}

// --------------------------------------------------------------------------
// Main: one wave per superrow iteration. Group g (float4 of 4 flat output
// elems) reads 4 packed entries from LDS (one ds_read_b128), gathers from the
// wave-uniform xp superrow (L1 broadcast), stores one aligned dwordx4.
// --------------------------------------------------------------------------
__global__ void __launch_bounds__(256)
poly_super(const float* __restrict__ xp, const uint32_t* __restrict__ ptbl,
           floatx4* __restrict__ out4) {
    __shared__ uint32_t s_tbl[4 * NCOLS];   // 15504 B
    for (int t = threadIdx.x; t < 4 * NCOLS; t += 256) s_tbl[t] = ptbl[t];
    __syncthreads();

    const int lane = threadIdx.x & 63;
    const int gw = blockIdx.x * 4 + (threadIdx.x >> 6);   // 0..8191

    for (int sr = gw; sr < SROWS; sr += 8192) {
        const char* xb = (const char*)(xp + (size_t)sr * (4 * XPAD));
        floatx4* op = out4 + (size_t)sr * GPS;

        #pragma unroll 5
        for (int u = 0; u < 15; ++u) {
            int g = u * 64 + lane;
            const uint32_t* pe = &s_tbl[g * 4];
            floatx4 v;
            #pragma unroll
            for (int q = 0; q < 4; ++q) {
                uint32_t p = pe[q];
                float a = *(const float*)(xb + (p & 0x1FFu));
                float b = *(const float*)(xb + ((p >> 9) & 0x1FFu));
                float c = *(const float*)(xb + ((p >> 18) & 0x1FFu));
                v[q] = (a * b) * c;   // left-to-right, matches jnp.prod
            }
            op[g] = v;
        }
        // tail: groups 960..968 (9 groups)
        if (lane < 9) {
            int g = 960 + lane;
            const uint32_t* pe = &s_tbl[g * 4];
            floatx4 v;
            #pragma unroll
            for (int q = 0; q < 4; ++q) {
                uint32_t p = pe[q];
                float a = *(const float*)(xb + (p & 0x1FFu));
                float b = *(const float*)(xb + ((p >> 9) & 0x1FFu));
                float c = *(const float*)(xb + ((p >> 18) & 0x1FFu));
                v[q] = (a * b) * c;
            }
            op[g] = v;
        }
    }
}

// --------------------------- fallback (round-3) ---------------------------
__global__ void poly_build_table(uint32_t* __restrict__ tbl) {
    for (int col = threadIdx.x; col < NCOLS; col += blockDim.x) {
        int i, j, k;
        decode_col(col, &i, &j, &k);
        uint32_t ui = (i == 16) ? 0xFFu : (uint32_t)i;
        uint32_t uj = (j == 16) ? 0xFFu : (uint32_t)j;
        uint32_t uk = (k == 16) ? 0xFFu : (uint32_t)k;
        tbl[col] = ui | (uj << 8) | (uk << 16);
    }
}

__global__ void __launch_bounds__(256)
poly_main4(const float* __restrict__ x, floatx4* __restrict__ out4,
           const uint32_t* __restrict__ tbl, int total4) {
    __shared__ uint32_t s_tbl[NCOLS];
    for (int t = threadIdx.x; t < NCOLS; t += blockDim.x) s_tbl[t] = tbl[t];
    __syncthreads();
    int idx = blockIdx.x * blockDim.x + threadIdx.x;
    int stride = gridDim.x * blockDim.x;
    for (int g4 = idx; g4 < total4; g4 += stride) {
        int g = g4 << 2;
        int row = g / NCOLS;
        int col = g - row * NCOLS;
        const float* xr = x + (row << 4);
        floatx4 pack;
        #pragma unroll
        for (int u = 0; u < 4; ++u) {
            uint32_t e = s_tbl[col];
            uint32_t i = e & 0xFFu, j = (e >> 8) & 0xFFu, k = (e >> 16) & 0xFFu;
            float p = 1.0f;
            if (i != 0xFFu) p = xr[i];
            if (j != 0xFFu) p *= xr[j];
            if (k != 0xFFu) p *= xr[k];
            pack[u] = p;
            if (++col == NCOLS) { col = 0; xr += NFEAT; }
        }
        out4[g4] = pack;
    }
}

// ---------------------------------------------------------------------------
extern "C" void kernel_launch(void* const* d_in, const int* in_sizes, int n_in,
                              void* d_out, int out_size, void* d_ws, size_t ws_size,
                              hipStream_t stream) {
    const float* x = (const float*)d_in[0];
    floatx4* out4 = (floatx4*)d_out;

    const size_t need = 16384 + (size_t)NROWS * XPAD * 4;   // ptbl + xp
    if (ws_size >= need) {
        uint32_t* ptbl = (uint32_t*)d_ws;
        float* xp = (float*)((char*)d_ws + 16384);
        build_packed<<<(4 * NCOLS + 255) / 256, 256, 0, stream>>>(ptbl);
        build_xp<<<(NROWS * XPAD + 255) / 256, 256, 0, stream>>>(x, xp);
        poly_super<<<2048, 256, 0, stream>>>(xp, ptbl, out4);
    } else {
        uint32_t* tbl = (uint32_t*)d_ws;
        poly_build_table<<<1, 256, 0, stream>>>(tbl);
        int total4 = out_size >> 2;
        int grid = (total4 + 255) / 256;
        if (grid > 2048) grid = 2048;
        poly_main4<<<grid, 256, 0, stream>>>(x, out4, tbl, total4);
    }
}

// Round 6
// 54.455 us; speedup vs baseline: 2.0104x; 1.5532x over previous
//
#include <hip/hip_runtime.h>
#include <stdint.h>

#define NFEAT 16
#define NCOLS 969            // 1 bias + 16 deg1 + 136 deg2 + 816 deg3
#define NROWS 65536
#define LSTRIDE 972          // dwords per LDS row: mult of 4 (16B f4 writes), %32=12 (bank spread)
#define PASS_ROWS 32
#define TILE_ROWS 64
#define TILES_PER_BLOCK 4    // 256 blocks * 4 tiles * 64 rows = 65536
#define PASS_ELEMS (PASS_ROWS * NCOLS)   // 31008 dwords, flat-contiguous in out

typedef float floatx4 __attribute__((ext_vector_type(4)));

// ---------------------------------------------------------------------------
// Static compute of cols [CBASE, CEND) of one row into LDS. All 969 columns
// emitted in sklearn/jax reference order (verified absmax 0.0 in R1/R3/R4/R5);
// out-of-range emits are compile-time dead. Zero decode, zero gathers.
// ---------------------------------------------------------------------------
template<int CBASE, int CEND>
__device__ __forceinline__ void compute_range(const float* xr, float* ldsrow) {
    float buf[4];
    int col = 0;
#define EMIT(P) do { \
    if (col >= CBASE && col < CEND) { \
        buf[(col - CBASE) & 3] = (P); \
        if (((col - CBASE) & 3) == 3) { \
            floatx4 p; p[0] = buf[0]; p[1] = buf[1]; p[2] = buf[2]; p[3] = buf[3]; \
            *(floatx4*)&ldsrow[col - 3] = p; /* CBASE%4==0 -> col-3 is 16B-aligned */ \
        } \
    } \
    ++col; } while (0)
    EMIT(1.0f);                                   // bias
    #pragma unroll
    for (int i = 0; i < NFEAT; ++i) EMIT(xr[i]);  // degree 1
    #pragma unroll
    for (int i = 0; i < NFEAT; ++i)               // degree 2
        #pragma unroll
        for (int j = i; j < NFEAT; ++j) EMIT(xr[i] * xr[j]);
    #pragma unroll
    for (int i = 0; i < NFEAT; ++i)               // degree 3 (reuses x_i*x_j via CSE)
        #pragma unroll
        for (int j = i; j < NFEAT; ++j)
            #pragma unroll
            for (int k = j; k < NFEAT; ++k) EMIT((xr[i] * xr[j]) * xr[k]);
#undef EMIT
    constexpr int rem = (CEND - CBASE) & 3;       // ragged tail (only range 7: 1 elem)
    if constexpr (rem != 0) {
        #pragma unroll
        for (int e = 0; e < rem; ++e) ldsrow[CEND - rem + e] = buf[e];
    }
}

__device__ __forceinline__ void compute_dispatch(int range, const float* xr, float* ldsrow) {
    switch (range) {   // range is uniform per 32-lane half-wave -> 2-way wave divergence max
        case 0: compute_range<  0, 124>(xr, ldsrow); break;
        case 1: compute_range<124, 248>(xr, ldsrow); break;
        case 2: compute_range<248, 372>(xr, ldsrow); break;
        case 3: compute_range<372, 496>(xr, ldsrow); break;
        case 4: compute_range<496, 620>(xr, ldsrow); break;
        case 5: compute_range<620, 744>(xr, ldsrow); break;
        case 6: compute_range<744, 868>(xr, ldsrow); break;
        case 7: compute_range<868, 969>(xr, ldsrow); break;
    }
}

// Flat contiguous copy LDS -> out for one 32-row pass (31008 dwords).
// Wave stores are 256B contiguous; LDS reads stride-1 (conflict-free).
__device__ __forceinline__ void store_pass(float* __restrict__ out, int rowbase,
                                           int tid, const float* lds) {
    float* dst = out + (size_t)rowbase * NCOLS;
    #pragma unroll 4
    for (int g = tid; g < PASS_ELEMS; g += 256) {
        int r = g / NCOLS;              // constant divisor -> magic multiply
        int c = g - r * NCOLS;
        __builtin_nontemporal_store(lds[r * LSTRIDE + c], dst + g);
    }
}

__global__ void __launch_bounds__(256, 1)
poly_rows(const float* __restrict__ x, float* __restrict__ out) {
    __shared__ float lds[PASS_ROWS * LSTRIDE];   // 124,416 B -> 1 block/CU

    const int tid  = threadIdx.x;
    const int lane = tid & 63;
    const int half = lane >> 5;                  // 0/1: half-wave id
    const int lrow = lane & 31;                  // row within pass
    const int range = ((tid >> 6) << 1) + half;  // 0..7, uniform per half-wave
    float* ldsrow = &lds[lrow * LSTRIDE];

    for (int it = 0; it < TILES_PER_BLOCK; ++it) {
        const int row0 = (blockIdx.x * TILES_PER_BLOCK + it) * TILE_ROWS;

        // Each lane loads the two x-rows it computes with (pass A and pass B).
        const floatx4* xa = (const floatx4*)(x + (size_t)(row0 + lrow) * NFEAT);
        const floatx4* xb = (const floatx4*)(x + (size_t)(row0 + 32 + lrow) * NFEAT);
        floatx4 a0 = xa[0], a1 = xa[1], a2 = xa[2], a3 = xa[3];
        floatx4 b0 = xb[0], b1 = xb[1], b2 = xb[2], b3 = xb[3];
        float xrA[NFEAT] = {a0[0],a0[1],a0[2],a0[3], a1[0],a1[1],a1[2],a1[3],
                            a2[0],a2[1],a2[2],a2[3], a3[0],a3[1],a3[2],a3[3]};
        float xrB[NFEAT] = {b0[0],b0[1],b0[2],b0[3], b1[0],b1[1],b1[2],b1[3],
                            b2[0],b2[1],b2[2],b2[3], b3[0],b3[1],b3[2],b3[3]};

        // ---- pass A: rows row0..row0+31 ----
        compute_dispatch(range, xrA, ldsrow);
        __syncthreads();
        store_pass(out, row0, tid, lds);
        __syncthreads();
        // ---- pass B: rows row0+32..row0+63 ----
        compute_dispatch(range, xrB, ldsrow);
        __syncthreads();
        store_pass(out, row0 + 32, tid, lds);
        __syncthreads();
    }
}

extern "C" void kernel_launch(void* const* d_in, const int* in_sizes, int n_in,
                              void* d_out, int out_size, void* d_ws, size_t ws_size,
                              hipStream_t stream) {
    const float* x = (const float*)d_in[0];
    float* out = (float*)d_out;
    // 256 blocks (1 per CU, LDS-capped), 4 tiles of 64 rows each.
    poly_rows<<<256, 256, 0, stream>>>(x, out);
}